// Round 4
// baseline (346.600 us; speedup 1.0000x reference)
//
#include <hip/hip_runtime.h>

#define MD 8192
#define ND 8192
#define DD 256
#define KTOP 256
#define CAND_T0 0.25f
#define NCAP 4096
#define NPAD 4096

typedef unsigned int u32;
typedef unsigned short u16;
typedef unsigned long long u64;

// workspace layout (bytes)
#define OFF_R    0                 // double R[8192]   64 KB
#define OFF_C    65536             // double C[8192]   64 KB
#define OFF_CNT  131072            // int
#define OFF_CAND 131200            // u32 cand[4096]   16 KB
#define OFF_KEYS 163840            // u64 keys[4096]   32 KB
#define OFF_AH   262144            // u16 Ah[8192*256]  4 MB
#define OFF_AL   (OFF_AH + 4194304)
#define OFF_BH   (OFF_AL + 4194304)
#define OFF_BL   (OFF_BH + 4194304)
#define WS_REQ   (OFF_BL + 4194304)

using bf16x8 = __attribute__((ext_vector_type(8))) __bf16;
using f32x4  = __attribute__((ext_vector_type(4))) float;
using f32x16 = __attribute__((ext_vector_type(16))) float;

#define AS1 __attribute__((address_space(1)))
#define AS3 __attribute__((address_space(3)))

__device__ __forceinline__ u16 f2bf(float x) {
  union { float f; u32 u; } v; v.f = x;
  u32 r = v.u + 0x7fffu + ((v.u >> 16) & 1u);   // RNE
  return (u16)(r >> 16);
}
__device__ __forceinline__ float bf2f(u16 h) {
  union { float f; u32 u; } v; v.u = ((u32)h) << 16;
  return v.f;
}

__global__ void k_init(double* __restrict__ R, double* __restrict__ C, int* __restrict__ cnt) {
  int i = blockIdx.x * blockDim.x + threadIdx.x;
  if (i < MD) R[i] = 0.0;
  if (i < ND) C[i] = 0.0;
  if (i == 0) *cnt = 0;
}

// Fused: zero R/C/cnt + split both matrices into (hi, lo) bf16 planes.
// grid = 4096 blocks x 256 thr; blocks [0,2048) -> A, [2048,4096) -> B.
__global__ __launch_bounds__(256) void k_prep2(
    const float* __restrict__ A, const float* __restrict__ B,
    u16* __restrict__ Ahp, u16* __restrict__ Alp,
    u16* __restrict__ Bhp, u16* __restrict__ Blp,
    double* __restrict__ R, double* __restrict__ C, int* __restrict__ cnt) {
  const int b = blockIdx.x, tid = threadIdx.x;
  const int gid = b * 256 + tid;
  if (gid < MD) R[gid] = 0.0;
  else if (gid < MD + ND) C[gid - MD] = 0.0;
  if (gid == 0) *cnt = 0;

  const float* X; u16 *hp, *lp; int i;
  if (b < 2048) { X = A; hp = Ahp; lp = Alp; i = gid; }
  else          { X = B; hp = Bhp; lp = Blp; i = gid - 2048 * 256; }
  float4 v = ((const float4*)X)[i];
  ushort4 h, l;
  h.x = f2bf(v.x); l.x = f2bf(v.x - bf2f(h.x));
  h.y = f2bf(v.y); l.y = f2bf(v.y - bf2f(h.y));
  h.z = f2bf(v.z); l.z = f2bf(v.z - bf2f(h.z));
  h.w = f2bf(v.w); l.w = f2bf(v.w - bf2f(h.w));
  ((ushort4*)hp)[i] = h;
  ((ushort4*)lp)[i] = l;
}

// ---------------- MFMA split-bf16 GEMM, 32x32x16 shape ----------------
// Block tile 256x128, 4 waves each 128x64 (4x2 tiles of 32x32), BK=32.
// c = ah*bh + ah*bl + al*bh accumulated fp32 in MFMA.
// A frag layout: A[m=lane&31][k=(lane>>5)*8+j]; C/D: col=lane&31,
// row=(reg&3)+8*(reg>>2)+4*(lane>>5)  (m74/m101).
__global__ __launch_bounds__(256, 2) void k_gemm_mfma(
    const u16* __restrict__ Ah, const u16* __restrict__ Al,
    const u16* __restrict__ Bh, const u16* __restrict__ Bl,
    double* __restrict__ R, double* __restrict__ C,
    int* __restrict__ cnt, u32* __restrict__ cand, int ncap) {
  __shared__ u16 sAh[256][32];
  __shared__ u16 sAl[256][32];
  __shared__ u16 sBh[128][32];
  __shared__ u16 sBl[128][32];

  const int tid = threadIdx.x;
  const int lane = tid & 63;
  const int wid = tid >> 6;
  const int wrow = wid >> 1, wcol = wid & 1;
  const int rowBase = blockIdx.y * 256;
  const int colBase = blockIdx.x * 128;
  const int lo5 = lane & 31, hi1 = lane >> 5;

  u16* lb; const u16* gb; int nch;
  if (wid == 0)      { lb = &sAh[0][0]; gb = Ah + (size_t)rowBase * DD; nch = 16; }
  else if (wid == 1) { lb = &sAl[0][0]; gb = Al + (size_t)rowBase * DD; nch = 16; }
  else if (wid == 2) { lb = &sBh[0][0]; gb = Bh + (size_t)colBase * DD; nch = 8; }
  else               { lb = &sBl[0][0]; gb = Bl + (size_t)colBase * DD; nch = 8; }

  f32x16 acc[4][2];
#pragma unroll
  for (int i = 0; i < 4; ++i)
#pragma unroll
    for (int j = 0; j < 2; ++j)
#pragma unroll
      for (int r = 0; r < 16; ++r) acc[i][j][r] = 0.f;

  for (int kt = 0; kt < 8; ++kt) {
    const int kk = kt * 32;
    for (int ch = 0; ch < nch; ++ch) {
      const u16* gp = gb + (size_t)(ch * 16 + (lane >> 2)) * DD + kk + (lane & 3) * 8;
      __builtin_amdgcn_global_load_lds((const AS1 void*)gp, (AS3 void*)(lb + ch * 512), 16, 0, 0);
    }
    __syncthreads();
#pragma unroll
    for (int h = 0; h < 2; ++h) {
      const int ko = h * 16 + hi1 * 8;
      bf16x8 fah[4], fal[4], fbh[2], fbl[2];
#pragma unroll
      for (int t = 0; t < 4; ++t) {
        fah[t] = *(const bf16x8*)&sAh[wrow * 128 + t * 32 + lo5][ko];
        fal[t] = *(const bf16x8*)&sAl[wrow * 128 + t * 32 + lo5][ko];
      }
#pragma unroll
      for (int t = 0; t < 2; ++t) {
        fbh[t] = *(const bf16x8*)&sBh[wcol * 64 + t * 32 + lo5][ko];
        fbl[t] = *(const bf16x8*)&sBl[wcol * 64 + t * 32 + lo5][ko];
      }
#pragma unroll
      for (int i = 0; i < 4; ++i)
#pragma unroll
        for (int j = 0; j < 2; ++j) {
          acc[i][j] = __builtin_amdgcn_mfma_f32_32x32x16_bf16(fah[i], fbh[j], acc[i][j], 0, 0, 0);
          acc[i][j] = __builtin_amdgcn_mfma_f32_32x32x16_bf16(fah[i], fbl[j], acc[i][j], 0, 0, 0);
          acc[i][j] = __builtin_amdgcn_mfma_f32_32x32x16_bf16(fal[i], fbh[j], acc[i][j], 0, 0, 0);
        }
    }
    __syncthreads();
  }

  // epilogue: e = exp(2c-2); fp64 row/col sums + candidates.
  double colp[2] = {0.0, 0.0};
#pragma unroll
  for (int i = 0; i < 4; ++i) {
#pragma unroll
    for (int r = 0; r < 16; ++r) {
      const int row = rowBase + wrow * 128 + i * 32 + (r & 3) + 8 * (r >> 2) + 4 * hi1;
      double rp = 0.0;
#pragma unroll
      for (int j = 0; j < 2; ++j) {
        float c = acc[i][j][r];
        float e = __expf(2.f * c - 2.f);
        rp += (double)e;
        colp[j] += (double)e;
        if (c >= CAND_T0) {
          int col = colBase + wcol * 64 + j * 32 + lo5;
          int idx = atomicAdd(cnt, 1);
          if (idx < ncap) cand[idx] = ((u32)row << 13) | (u32)col;
        }
      }
#pragma unroll
      for (int off = 16; off; off >>= 1) rp += __shfl_xor(rp, off, 32);
      if (lo5 == 0) atomicAdd(&R[row], rp);
    }
  }
#pragma unroll
  for (int j = 0; j < 2; ++j) {
    double v = colp[j];
    v += __shfl_xor(v, 32, 64);
    if (hi1 == 0) atomicAdd(&C[colBase + wcol * 64 + j * 32 + lo5], v);
  }
}

// ---------------- fp32 fallback GEMM (used only if ws too small) ----------------
__global__ __launch_bounds__(256) void k_gemm_f32(
    const float* __restrict__ A, const float* __restrict__ B,
    double* __restrict__ R, double* __restrict__ C,
    int* __restrict__ cnt, u32* __restrict__ cand, int ncap) {
  __shared__ float As[32][128];
  __shared__ float Bs[32][128];
  __shared__ double colLds[16][128];
  const int tid = threadIdx.x;
  const int tx = tid & 15, ty = tid >> 4;
  const int rowBase = blockIdx.y * 128;
  const int colBase = blockIdx.x * 128;
  float acc[8][8];
#pragma unroll
  for (int i = 0; i < 8; ++i)
#pragma unroll
    for (int j = 0; j < 8; ++j) acc[i][j] = 0.f;
  const int lr = tid >> 3;
  const int lc = (tid & 7) << 2;
  for (int kk = 0; kk < DD; kk += 32) {
#pragma unroll
    for (int r = 0; r < 4; ++r) {
      int row = lr + r * 32;
      float4 av = *(const float4*)(A + (size_t)(rowBase + row) * DD + kk + lc);
      float4 bv = *(const float4*)(B + (size_t)(colBase + row) * DD + kk + lc);
      As[lc + 0][row] = av.x; As[lc + 1][row] = av.y; As[lc + 2][row] = av.z; As[lc + 3][row] = av.w;
      Bs[lc + 0][row] = bv.x; Bs[lc + 1][row] = bv.y; Bs[lc + 2][row] = bv.z; Bs[lc + 3][row] = bv.w;
    }
    __syncthreads();
#pragma unroll 4
    for (int k = 0; k < 32; ++k) {
      float a[8], b[8];
      *(float4*)(a + 0) = *(const float4*)(&As[k][ty * 8 + 0]);
      *(float4*)(a + 4) = *(const float4*)(&As[k][ty * 8 + 4]);
      *(float4*)(b + 0) = *(const float4*)(&Bs[k][tx * 8 + 0]);
      *(float4*)(b + 4) = *(const float4*)(&Bs[k][tx * 8 + 4]);
#pragma unroll
      for (int i = 0; i < 8; ++i)
#pragma unroll
        for (int j = 0; j < 8; ++j)
          acc[i][j] = fmaf(a[i], b[j], acc[i][j]);
    }
    __syncthreads();
  }
  double colpart[8];
#pragma unroll
  for (int j = 0; j < 8; ++j) colpart[j] = 0.0;
#pragma unroll
  for (int i = 0; i < 8; ++i) {
    double rp = 0.0;
#pragma unroll
    for (int j = 0; j < 8; ++j) {
      float e = __expf(2.f * acc[i][j] - 2.f);
      rp += (double)e;
      colpart[j] += (double)e;
    }
#pragma unroll
    for (int off = 8; off; off >>= 1) rp += __shfl_down(rp, off, 16);
    if (tx == 0) atomicAdd(&R[rowBase + ty * 8 + i], rp);
  }
#pragma unroll
  for (int j = 0; j < 8; ++j) colLds[ty][tx * 8 + j] = colpart[j];
  __syncthreads();
  if (tid < 128) {
    double s = 0.0;
#pragma unroll
    for (int t = 0; t < 16; ++t) s += colLds[t][tid];
    atomicAdd(&C[colBase + tid], s);
  }
#pragma unroll
  for (int i = 0; i < 8; ++i)
#pragma unroll
    for (int j = 0; j < 8; ++j) {
      if (acc[i][j] >= CAND_T0) {
        int idx = atomicAdd(cnt, 1);
        if (idx < ncap)
          cand[idx] = ((u32)(rowBase + ty * 8 + i) << 13) | (u32)(colBase + tx * 8 + j);
      }
    }
}

// One wave per candidate: exact fp64 dot, fp64 score, orderable u64 key.
__global__ __launch_bounds__(256) void k_score(
    const float* __restrict__ A, const float* __restrict__ B,
    const double* __restrict__ R, const double* __restrict__ C,
    const int* __restrict__ cnt, const u32* __restrict__ cand,
    u64* __restrict__ keys, int ncap) {
  int w = (int)((blockIdx.x * 256 + threadIdx.x) >> 6);
  int lane = threadIdx.x & 63;
  int n = *cnt; if (n > ncap) n = ncap;
  if (w >= n) return;
  u32 mn = cand[w];
  int m = (int)(mn >> 13), nn = (int)(mn & 8191u);
  const float* ar = A + (size_t)m * DD;
  const float* br = B + (size_t)nn * DD;
  double s = 0.0;
#pragma unroll
  for (int d = 0; d < DD; d += 64)
    s = fma((double)ar[d + lane], (double)br[d + lane], s);
#pragma unroll
  for (int off = 32; off; off >>= 1) s += __shfl_down(s, off);
  if (lane == 0) {
    double sc = exp(4.0 * s - 4.0) / (R[m] * C[nn]);
    keys[w] = (u64)__double_as_longlong(sc);
  }
}

// Single-block LDS bitonic sort (key desc, flat-idx asc) -> top-256.
// Sorts only the next pow2 >= candidate count.
__global__ __launch_bounds__(1024) void k_sort(
    const int* __restrict__ cnt, const u32* __restrict__ cand,
    const u64* __restrict__ keys, float* __restrict__ out, int ncap) {
  extern __shared__ char smem[];
  u64* sk = (u64*)smem;
  u32* sm = (u32*)(smem + (size_t)NPAD * 8);
  const int tid = threadIdx.x;
  int m = *cnt; if (m > ncap) m = ncap; if (m > NPAD) m = NPAD;
  int np = KTOP; while (np < m) np <<= 1;   // pow2, >= KTOP, <= NPAD

  for (int i = tid; i < np; i += 1024) { sk[i] = 0; sm[i] = 0xFFFFFFFFu; }
  __syncthreads();
  for (int i = tid; i < m; i += 1024) { sk[i] = keys[i]; sm[i] = cand[i]; }
  __syncthreads();

  for (unsigned k = 2; k <= (unsigned)np; k <<= 1) {
    for (unsigned j = k >> 1; j > 0; j >>= 1) {
      for (unsigned i = tid; i < (unsigned)np; i += 1024) {
        unsigned l = i ^ j;
        if (l > i) {
          u64 ki = sk[i], kl = sk[l];
          u32 mi = sm[i], ml = sm[l];
          bool dir = ((i & k) == 0);
          bool i_worse = (ki < kl) || (ki == kl && mi > ml);
          bool l_worse = (kl < ki) || (kl == ki && ml > mi);
          if (dir ? i_worse : l_worse) {
            sk[i] = kl; sk[l] = ki; sm[i] = ml; sm[l] = mi;
          }
        }
      }
      __syncthreads();
    }
  }

  for (int r = tid; r < KTOP; r += 1024) {
    u32 mn = sm[r];
    u64 kk = sk[r];
    out[r] = (float)(mn >> 13);
    out[KTOP + r] = (float)(mn & 8191u);
    out[2 * KTOP + r] = (float)__longlong_as_double((long long)kk);
  }
}

extern "C" void kernel_launch(void* const* d_in, const int* in_sizes, int n_in,
                              void* d_out, int out_size, void* d_ws, size_t ws_size,
                              hipStream_t stream) {
  (void)in_sizes; (void)n_in; (void)out_size;
  const float* A = (const float*)d_in[0];  // ref_feats [8192,256]
  const float* B = (const float*)d_in[1];  // src_feats [8192,256]
  float* out = (float*)d_out;
  char* ws = (char*)d_ws;
  double* R = (double*)(ws + OFF_R);
  double* C = (double*)(ws + OFF_C);
  int* cnt = (int*)(ws + OFF_CNT);
  u32* cand = (u32*)(ws + OFF_CAND);
  u64* keys = (u64*)(ws + OFF_KEYS);

  if (ws_size >= (size_t)WS_REQ) {
    u16* Ahp = (u16*)(ws + OFF_AH);
    u16* Alp = (u16*)(ws + OFF_AL);
    u16* Bhp = (u16*)(ws + OFF_BH);
    u16* Blp = (u16*)(ws + OFF_BL);
    hipLaunchKernelGGL(k_prep2, dim3(4096), dim3(256), 0, stream,
                       A, B, Ahp, Alp, Bhp, Blp, R, C, cnt);
    hipLaunchKernelGGL(k_gemm_mfma, dim3(ND / 128, MD / 256), dim3(256), 0, stream,
                       Ahp, Alp, Bhp, Blp, R, C, cnt, cand, NCAP);
  } else {
    hipLaunchKernelGGL(k_init, dim3(32), dim3(256), 0, stream, R, C, cnt);
    hipLaunchKernelGGL(k_gemm_f32, dim3(ND / 128, MD / 128), dim3(256), 0, stream,
                       A, B, R, C, cnt, cand, NCAP);
  }

  hipLaunchKernelGGL(k_score, dim3(NCAP / 4), dim3(256), 0, stream,
                     A, B, R, C, cnt, cand, keys, NCAP);
  hipLaunchKernelGGL(k_sort, dim3(1), dim3(1024), (size_t)NPAD * 12, stream,
                     cnt, cand, keys, out, NCAP);
}

// Round 5
// 267.469 us; speedup vs baseline: 1.2959x; 1.2959x over previous
//
#include <hip/hip_runtime.h>

#define MD 8192
#define ND 8192
#define DD 256
#define KTOP 256
#define CAND_T0 0.25f
#define NCAP 4096
#define NPAD 4096

typedef unsigned int u32;
typedef unsigned short u16;
typedef unsigned long long u64;

// workspace layout (bytes)
#define OFF_R    0                 // double R[8192]   64 KB
#define OFF_C    65536             // double C[8192]   64 KB
#define OFF_CNT  131072            // int
#define OFF_CAND 131200            // u32 cand[4096]   16 KB
#define OFF_KEYS 163840            // u64 keys[4096]   32 KB
#define OFF_AH   262144            // u16 Ah[8192*256]  4 MB
#define OFF_AL   (OFF_AH + 4194304)
#define OFF_BH   (OFF_AL + 4194304)
#define OFF_BL   (OFF_BH + 4194304)
#define WS_REQ   (OFF_BL + 4194304)

using bf16x8 = __attribute__((ext_vector_type(8))) __bf16;
using f32x4  = __attribute__((ext_vector_type(4))) float;

#define AS1 __attribute__((address_space(1)))
#define AS3 __attribute__((address_space(3)))

__device__ __forceinline__ u16 f2bf(float x) {
  union { float f; u32 u; } v; v.f = x;
  u32 r = v.u + 0x7fffu + ((v.u >> 16) & 1u);   // RNE
  return (u16)(r >> 16);
}
__device__ __forceinline__ float bf2f(u16 h) {
  union { float f; u32 u; } v; v.u = ((u32)h) << 16;
  return v.f;
}

__global__ void k_init(double* __restrict__ R, double* __restrict__ C, int* __restrict__ cnt) {
  int i = blockIdx.x * blockDim.x + threadIdx.x;
  if (i < MD) R[i] = 0.0;
  if (i < ND) C[i] = 0.0;
  if (i == 0) *cnt = 0;
}

// Fused: zero R/C/cnt + split both matrices into (hi, lo) bf16 planes.
__global__ __launch_bounds__(256) void k_prep2(
    const float* __restrict__ A, const float* __restrict__ B,
    u16* __restrict__ Ahp, u16* __restrict__ Alp,
    u16* __restrict__ Bhp, u16* __restrict__ Blp,
    double* __restrict__ R, double* __restrict__ C, int* __restrict__ cnt) {
  const int b = blockIdx.x, tid = threadIdx.x;
  const int gid = b * 256 + tid;
  if (gid < MD) R[gid] = 0.0;
  else if (gid < MD + ND) C[gid - MD] = 0.0;
  if (gid == 0) *cnt = 0;

  const float* X; u16 *hp, *lp; int i;
  if (b < 2048) { X = A; hp = Ahp; lp = Alp; i = gid; }
  else          { X = B; hp = Bhp; lp = Blp; i = gid - 2048 * 256; }
  float4 v = ((const float4*)X)[i];
  ushort4 h, l;
  h.x = f2bf(v.x); l.x = f2bf(v.x - bf2f(h.x));
  h.y = f2bf(v.y); l.y = f2bf(v.y - bf2f(h.y));
  h.z = f2bf(v.z); l.z = f2bf(v.z - bf2f(h.z));
  h.w = f2bf(v.w); l.w = f2bf(v.w - bf2f(h.w));
  ((ushort4*)hp)[i] = h;
  ((ushort4*)lp)[i] = l;
}

// ---------------- MFMA split-bf16 GEMM (R3 structure + XOR bank swizzle) ----
// 128x128 tile, BK=32, 4 waves each 64x64 (4x4 tiles of 16x16).
// c = ah*bh + ah*bl + al*bh, fp32 MFMA accumulate.
// LDS swizzle: 16B chunk c of row r stored at position c ^ ((r>>1)&3).
// Staging keeps contiguous lane deposits; lane fetches the swizzled chunk.
__global__ __launch_bounds__(256, 2) void k_gemm_mfma(
    const u16* __restrict__ Ah, const u16* __restrict__ Al,
    const u16* __restrict__ Bh, const u16* __restrict__ Bl,
    double* __restrict__ R, double* __restrict__ C,
    int* __restrict__ cnt, u32* __restrict__ cand, int ncap) {
  __shared__ u16 sAh[128][32];
  __shared__ u16 sAl[128][32];
  __shared__ u16 sBh[128][32];
  __shared__ u16 sBl[128][32];

  const int tid = threadIdx.x;
  const int lane = tid & 63;
  const int wid = tid >> 6;           // 0..3
  const int wrow = wid >> 1, wcol = wid & 1;
  const int rowBase = blockIdx.y * 128;
  const int colBase = blockIdx.x * 128;
  const int quad = lane >> 4, lo = lane & 15;
  const int sw = (lo >> 1) & 3;       // per-lane read swizzle
  const int cswz = (lane & 3) ^ ((lane >> 3) & 3);  // staging fetch swizzle

  u16* lb;
  const u16* gb;
  if (wid == 0)      { lb = &sAh[0][0]; gb = Ah + (size_t)rowBase * DD; }
  else if (wid == 1) { lb = &sAl[0][0]; gb = Al + (size_t)rowBase * DD; }
  else if (wid == 2) { lb = &sBh[0][0]; gb = Bh + (size_t)colBase * DD; }
  else               { lb = &sBl[0][0]; gb = Bl + (size_t)colBase * DD; }

  f32x4 acc[4][4];
#pragma unroll
  for (int i = 0; i < 4; ++i)
#pragma unroll
    for (int j = 0; j < 4; ++j) acc[i][j] = (f32x4){0.f, 0.f, 0.f, 0.f};

  for (int kt = 0; kt < 8; ++kt) {
    const int kk = kt * 32;
#pragma unroll
    for (int ch = 0; ch < 8; ++ch) {
      const u16* gp = gb + (size_t)(ch * 16 + (lane >> 2)) * DD + kk + cswz * 8;
      __builtin_amdgcn_global_load_lds((const AS1 void*)gp, (AS3 void*)(lb + ch * 512), 16, 0, 0);
    }
    __syncthreads();

    bf16x8 fah[4], fal[4], fbh[4], fbl[4];
    const int cq = (quad ^ sw) * 8;
#pragma unroll
    for (int t = 0; t < 4; ++t) {
      fah[t] = *(const bf16x8*)&sAh[wrow * 64 + t * 16 + lo][cq];
      fal[t] = *(const bf16x8*)&sAl[wrow * 64 + t * 16 + lo][cq];
      fbh[t] = *(const bf16x8*)&sBh[wcol * 64 + t * 16 + lo][cq];
      fbl[t] = *(const bf16x8*)&sBl[wcol * 64 + t * 16 + lo][cq];
    }
#pragma unroll
    for (int i = 0; i < 4; ++i)
#pragma unroll
      for (int j = 0; j < 4; ++j) {
        acc[i][j] = __builtin_amdgcn_mfma_f32_16x16x32_bf16(fah[i], fbh[j], acc[i][j], 0, 0, 0);
        acc[i][j] = __builtin_amdgcn_mfma_f32_16x16x32_bf16(fah[i], fbl[j], acc[i][j], 0, 0, 0);
        acc[i][j] = __builtin_amdgcn_mfma_f32_16x16x32_bf16(fal[i], fbh[j], acc[i][j], 0, 0, 0);
      }
    __syncthreads();
  }

  // epilogue: e = exp(2c-2); fp64 row/col sums + candidates.
  // C/D layout: col = lo, row = quad*4 + reg  (m89/m91)
  double rowp[4][4];
  double colp[4];
#pragma unroll
  for (int i = 0; i < 4; ++i)
#pragma unroll
    for (int r = 0; r < 4; ++r) rowp[i][r] = 0.0;
#pragma unroll
  for (int j = 0; j < 4; ++j) colp[j] = 0.0;

#pragma unroll
  for (int i = 0; i < 4; ++i)
#pragma unroll
    for (int j = 0; j < 4; ++j)
#pragma unroll
      for (int r = 0; r < 4; ++r) {
        float c = acc[i][j][r];
        float e = __expf(2.f * c - 2.f);
        rowp[i][r] += (double)e;
        colp[j] += (double)e;
        if (c >= CAND_T0) {
          int row = rowBase + wrow * 64 + i * 16 + quad * 4 + r;
          int col = colBase + wcol * 64 + j * 16 + lo;
          int idx = atomicAdd(cnt, 1);
          if (idx < ncap) cand[idx] = ((u32)row << 13) | (u32)col;
        }
      }

#pragma unroll
  for (int i = 0; i < 4; ++i)
#pragma unroll
    for (int r = 0; r < 4; ++r) {
      double v = rowp[i][r];
#pragma unroll
      for (int off = 8; off; off >>= 1) v += __shfl_xor(v, off, 16);
      if (lo == 0) {
        int row = rowBase + wrow * 64 + i * 16 + quad * 4 + r;
        atomicAdd(&R[row], v);
      }
    }
#pragma unroll
  for (int j = 0; j < 4; ++j) {
    double v = colp[j];
    v += __shfl_xor(v, 16);
    v += __shfl_xor(v, 32);
    if (quad == 0) {
      int col = colBase + wcol * 64 + j * 16 + lo;
      atomicAdd(&C[col], v);
    }
  }
}

// ---------------- fp32 fallback GEMM (used only if ws too small) ----------------
__global__ __launch_bounds__(256) void k_gemm_f32(
    const float* __restrict__ A, const float* __restrict__ B,
    double* __restrict__ R, double* __restrict__ C,
    int* __restrict__ cnt, u32* __restrict__ cand, int ncap) {
  __shared__ float As[32][128];
  __shared__ float Bs[32][128];
  __shared__ double colLds[16][128];
  const int tid = threadIdx.x;
  const int tx = tid & 15, ty = tid >> 4;
  const int rowBase = blockIdx.y * 128;
  const int colBase = blockIdx.x * 128;
  float acc[8][8];
#pragma unroll
  for (int i = 0; i < 8; ++i)
#pragma unroll
    for (int j = 0; j < 8; ++j) acc[i][j] = 0.f;
  const int lr = tid >> 3;
  const int lc = (tid & 7) << 2;
  for (int kk = 0; kk < DD; kk += 32) {
#pragma unroll
    for (int r = 0; r < 4; ++r) {
      int row = lr + r * 32;
      float4 av = *(const float4*)(A + (size_t)(rowBase + row) * DD + kk + lc);
      float4 bv = *(const float4*)(B + (size_t)(colBase + row) * DD + kk + lc);
      As[lc + 0][row] = av.x; As[lc + 1][row] = av.y; As[lc + 2][row] = av.z; As[lc + 3][row] = av.w;
      Bs[lc + 0][row] = bv.x; Bs[lc + 1][row] = bv.y; Bs[lc + 2][row] = bv.z; Bs[lc + 3][row] = bv.w;
    }
    __syncthreads();
#pragma unroll 4
    for (int k = 0; k < 32; ++k) {
      float a[8], b[8];
      *(float4*)(a + 0) = *(const float4*)(&As[k][ty * 8 + 0]);
      *(float4*)(a + 4) = *(const float4*)(&As[k][ty * 8 + 4]);
      *(float4*)(b + 0) = *(const float4*)(&Bs[k][tx * 8 + 0]);
      *(float4*)(b + 4) = *(const float4*)(&Bs[k][tx * 8 + 4]);
#pragma unroll
      for (int i = 0; i < 8; ++i)
#pragma unroll
        for (int j = 0; j < 8; ++j)
          acc[i][j] = fmaf(a[i], b[j], acc[i][j]);
    }
    __syncthreads();
  }
  double colpart[8];
#pragma unroll
  for (int j = 0; j < 8; ++j) colpart[j] = 0.0;
#pragma unroll
  for (int i = 0; i < 8; ++i) {
    double rp = 0.0;
#pragma unroll
    for (int j = 0; j < 8; ++j) {
      float e = __expf(2.f * acc[i][j] - 2.f);
      rp += (double)e;
      colpart[j] += (double)e;
    }
#pragma unroll
    for (int off = 8; off; off >>= 1) rp += __shfl_down(rp, off, 16);
    if (tx == 0) atomicAdd(&R[rowBase + ty * 8 + i], rp);
  }
#pragma unroll
  for (int j = 0; j < 8; ++j) colLds[ty][tx * 8 + j] = colpart[j];
  __syncthreads();
  if (tid < 128) {
    double s = 0.0;
#pragma unroll
    for (int t = 0; t < 16; ++t) s += colLds[t][tid];
    atomicAdd(&C[colBase + tid], s);
  }
#pragma unroll
  for (int i = 0; i < 8; ++i)
#pragma unroll
    for (int j = 0; j < 8; ++j) {
      if (acc[i][j] >= CAND_T0) {
        int idx = atomicAdd(cnt, 1);
        if (idx < ncap)
          cand[idx] = ((u32)(rowBase + ty * 8 + i) << 13) | (u32)(colBase + tx * 8 + j);
      }
    }
}

// One wave per candidate: exact fp64 dot, fp64 score, orderable u64 key.
__global__ __launch_bounds__(256) void k_score(
    const float* __restrict__ A, const float* __restrict__ B,
    const double* __restrict__ R, const double* __restrict__ C,
    const int* __restrict__ cnt, const u32* __restrict__ cand,
    u64* __restrict__ keys, int ncap) {
  int w = (int)((blockIdx.x * 256 + threadIdx.x) >> 6);
  int lane = threadIdx.x & 63;
  int n = *cnt; if (n > ncap) n = ncap;
  if (w >= n) return;
  u32 mn = cand[w];
  int m = (int)(mn >> 13), nn = (int)(mn & 8191u);
  const float* ar = A + (size_t)m * DD;
  const float* br = B + (size_t)nn * DD;
  double s = 0.0;
#pragma unroll
  for (int d = 0; d < DD; d += 64)
    s = fma((double)ar[d + lane], (double)br[d + lane], s);
#pragma unroll
  for (int off = 32; off; off >>= 1) s += __shfl_down(s, off);
  if (lane == 0) {
    double sc = exp(4.0 * s - 4.0) / (R[m] * C[nn]);
    keys[w] = (u64)__double_as_longlong(sc);
  }
}

// Single-block LDS bitonic sort (key desc, flat-idx asc) -> top-256.
__global__ __launch_bounds__(1024) void k_sort(
    const int* __restrict__ cnt, const u32* __restrict__ cand,
    const u64* __restrict__ keys, float* __restrict__ out, int ncap) {
  extern __shared__ char smem[];
  u64* sk = (u64*)smem;
  u32* sm = (u32*)(smem + (size_t)NPAD * 8);
  const int tid = threadIdx.x;
  int m = *cnt; if (m > ncap) m = ncap; if (m > NPAD) m = NPAD;
  int np = KTOP; while (np < m) np <<= 1;

  for (int i = tid; i < np; i += 1024) { sk[i] = 0; sm[i] = 0xFFFFFFFFu; }
  __syncthreads();
  for (int i = tid; i < m; i += 1024) { sk[i] = keys[i]; sm[i] = cand[i]; }
  __syncthreads();

  for (unsigned k = 2; k <= (unsigned)np; k <<= 1) {
    for (unsigned j = k >> 1; j > 0; j >>= 1) {
      for (unsigned i = tid; i < (unsigned)np; i += 1024) {
        unsigned l = i ^ j;
        if (l > i) {
          u64 ki = sk[i], kl = sk[l];
          u32 mi = sm[i], ml = sm[l];
          bool dir = ((i & k) == 0);
          bool i_worse = (ki < kl) || (ki == kl && mi > ml);
          bool l_worse = (kl < ki) || (kl == ki && ml > mi);
          if (dir ? i_worse : l_worse) {
            sk[i] = kl; sk[l] = ki; sm[i] = ml; sm[l] = mi;
          }
        }
      }
      __syncthreads();
    }
  }

  for (int r = tid; r < KTOP; r += 1024) {
    u32 mn = sm[r];
    u64 kk = sk[r];
    out[r] = (float)(mn >> 13);
    out[KTOP + r] = (float)(mn & 8191u);
    out[2 * KTOP + r] = (float)__longlong_as_double((long long)kk);
  }
}

extern "C" void kernel_launch(void* const* d_in, const int* in_sizes, int n_in,
                              void* d_out, int out_size, void* d_ws, size_t ws_size,
                              hipStream_t stream) {
  (void)in_sizes; (void)n_in; (void)out_size;
  const float* A = (const float*)d_in[0];  // ref_feats [8192,256]
  const float* B = (const float*)d_in[1];  // src_feats [8192,256]
  float* out = (float*)d_out;
  char* ws = (char*)d_ws;
  double* R = (double*)(ws + OFF_R);
  double* C = (double*)(ws + OFF_C);
  int* cnt = (int*)(ws + OFF_CNT);
  u32* cand = (u32*)(ws + OFF_CAND);
  u64* keys = (u64*)(ws + OFF_KEYS);

  if (ws_size >= (size_t)WS_REQ) {
    u16* Ahp = (u16*)(ws + OFF_AH);
    u16* Alp = (u16*)(ws + OFF_AL);
    u16* Bhp = (u16*)(ws + OFF_BH);
    u16* Blp = (u16*)(ws + OFF_BL);
    hipLaunchKernelGGL(k_prep2, dim3(4096), dim3(256), 0, stream,
                       A, B, Ahp, Alp, Bhp, Blp, R, C, cnt);
    hipLaunchKernelGGL(k_gemm_mfma, dim3(ND / 128, MD / 128), dim3(256), 0, stream,
                       Ahp, Alp, Bhp, Blp, R, C, cnt, cand, NCAP);
  } else {
    hipLaunchKernelGGL(k_init, dim3(32), dim3(256), 0, stream, R, C, cnt);
    hipLaunchKernelGGL(k_gemm_f32, dim3(ND / 128, MD / 128), dim3(256), 0, stream,
                       A, B, R, C, cnt, cand, NCAP);
  }

  hipLaunchKernelGGL(k_score, dim3(NCAP / 4), dim3(256), 0, stream,
                     A, B, R, C, cnt, cand, keys, NCAP);
  hipLaunchKernelGGL(k_sort, dim3(1), dim3(1024), (size_t)NPAD * 12, stream,
                     cnt, cand, keys, out, NCAP);
}

// Round 6
// 231.380 us; speedup vs baseline: 1.4980x; 1.1560x over previous
//
#include <hip/hip_runtime.h>

#define MD 8192
#define ND 8192
#define DD 256
#define KTOP 256
#define CAND_T0 0.25f
#define NCAP 4096
#define NPAD 4096

typedef unsigned int u32;
typedef unsigned short u16;
typedef unsigned long long u64;

// workspace layout (bytes)
#define OFF_R    0                 // double R[8192]   64 KB
#define OFF_C    65536             // double C[8192]   64 KB
#define OFF_CNT  131072            // int
#define OFF_CAND 131200            // u32 cand[4096]   16 KB
#define OFF_KEYS 163840            // u64 keys[4096]   32 KB
#define OFF_AH   262144            // u16 Ah[8192*256]  4 MB
#define OFF_AL   (OFF_AH + 4194304)
#define OFF_BH   (OFF_AL + 4194304)
#define OFF_BL   (OFF_BH + 4194304)
#define WS_REQ   (OFF_BL + 4194304)

using bf16x8 = __attribute__((ext_vector_type(8))) __bf16;
using f32x4  = __attribute__((ext_vector_type(4))) float;

#define AS1 __attribute__((address_space(1)))
#define AS3 __attribute__((address_space(3)))

__device__ __forceinline__ u16 f2bf(float x) {
  union { float f; u32 u; } v; v.f = x;
  u32 r = v.u + 0x7fffu + ((v.u >> 16) & 1u);   // RNE
  return (u16)(r >> 16);
}
__device__ __forceinline__ float bf2f(u16 h) {
  union { float f; u32 u; } v; v.u = ((u32)h) << 16;
  return v.f;
}

__global__ void k_init(double* __restrict__ R, double* __restrict__ C, int* __restrict__ cnt) {
  int i = blockIdx.x * blockDim.x + threadIdx.x;
  if (i < MD) R[i] = 0.0;
  if (i < ND) C[i] = 0.0;
  if (i == 0) *cnt = 0;
}

// Fused: zero R/C/cnt + split both matrices into (hi, lo) bf16 planes.
__global__ __launch_bounds__(256) void k_prep2(
    const float* __restrict__ A, const float* __restrict__ B,
    u16* __restrict__ Ahp, u16* __restrict__ Alp,
    u16* __restrict__ Bhp, u16* __restrict__ Blp,
    double* __restrict__ R, double* __restrict__ C, int* __restrict__ cnt) {
  const int b = blockIdx.x, tid = threadIdx.x;
  const int gid = b * 256 + tid;
  if (gid < MD) R[gid] = 0.0;
  else if (gid < MD + ND) C[gid - MD] = 0.0;
  if (gid == 0) *cnt = 0;

  const float* X; u16 *hp, *lp; int i;
  if (b < 2048) { X = A; hp = Ahp; lp = Alp; i = gid; }
  else          { X = B; hp = Bhp; lp = Blp; i = gid - 2048 * 256; }
  float4 v = ((const float4*)X)[i];
  ushort4 h, l;
  h.x = f2bf(v.x); l.x = f2bf(v.x - bf2f(h.x));
  h.y = f2bf(v.y); l.y = f2bf(v.y - bf2f(h.y));
  h.z = f2bf(v.z); l.z = f2bf(v.z - bf2f(h.z));
  h.w = f2bf(v.w); l.w = f2bf(v.w - bf2f(h.w));
  ((ushort4*)hp)[i] = h;
  ((ushort4*)lp)[i] = l;
}

// ---------------- MFMA split-bf16 GEMM ----------------
// 128x128 tile, BK=32, 4 waves each 64x64 (4x4 tiles of 16x16).
// c = ah*bh + ah*bl + al*bh, fp32 MFMA accumulate.
// XOR chunk swizzle keeps LDS conflict-free (R5, verified 0 conflicts).
// XCD swizzle: g&7 -> XCD; each XCD owns 8 row-tiles (A 1MB L2-resident),
// sweeps col-tiles so the active B window stays ~1.5MB (< 4MB/XCD L2).
// j-outer inner loop keeps only one B hi/lo frag pair live -> ~124 regs,
// targeting 4 waves/SIMD via __launch_bounds__(256,4).
__global__ __launch_bounds__(256, 4) void k_gemm_mfma(
    const u16* __restrict__ Ah, const u16* __restrict__ Al,
    const u16* __restrict__ Bh, const u16* __restrict__ Bl,
    double* __restrict__ R, double* __restrict__ C,
    int* __restrict__ cnt, u32* __restrict__ cand, int ncap) {
  __shared__ u16 sAh[128][32];
  __shared__ u16 sAl[128][32];
  __shared__ u16 sBh[128][32];
  __shared__ u16 sBl[128][32];

  const int tid = threadIdx.x;
  const int lane = tid & 63;
  const int wid = tid >> 6;           // 0..3
  const int wrow = wid >> 1, wcol = wid & 1;

  // XCD-aware block swizzle (1-D grid of 4096)
  const int g = blockIdx.x;
  const int xcd = g & 7;
  const int l = g >> 3;               // 0..511
  const int rowTile = xcd * 8 + (l & 7);
  const int colTile = l >> 3;
  const int rowBase = rowTile * 128;
  const int colBase = colTile * 128;

  const int quad = lane >> 4, lo = lane & 15;
  const int sw = (lo >> 1) & 3;
  const int cswz = (lane & 3) ^ ((lane >> 3) & 3);

  u16* lb;
  const u16* gb;
  if (wid == 0)      { lb = &sAh[0][0]; gb = Ah + (size_t)rowBase * DD; }
  else if (wid == 1) { lb = &sAl[0][0]; gb = Al + (size_t)rowBase * DD; }
  else if (wid == 2) { lb = &sBh[0][0]; gb = Bh + (size_t)colBase * DD; }
  else               { lb = &sBl[0][0]; gb = Bl + (size_t)colBase * DD; }

  f32x4 acc[4][4];
#pragma unroll
  for (int i = 0; i < 4; ++i)
#pragma unroll
    for (int j = 0; j < 4; ++j) acc[i][j] = (f32x4){0.f, 0.f, 0.f, 0.f};

  for (int kt = 0; kt < 8; ++kt) {
    const int kk = kt * 32;
#pragma unroll
    for (int ch = 0; ch < 8; ++ch) {
      const u16* gp = gb + (size_t)(ch * 16 + (lane >> 2)) * DD + kk + cswz * 8;
      __builtin_amdgcn_global_load_lds((const AS1 void*)gp, (AS3 void*)(lb + ch * 512), 16, 0, 0);
    }
    __syncthreads();

    const int cq = (quad ^ sw) * 8;
    bf16x8 fah[4], fal[4];
#pragma unroll
    for (int t = 0; t < 4; ++t) {
      fah[t] = *(const bf16x8*)&sAh[wrow * 64 + t * 16 + lo][cq];
      fal[t] = *(const bf16x8*)&sAl[wrow * 64 + t * 16 + lo][cq];
    }
#pragma unroll
    for (int j = 0; j < 4; ++j) {
      bf16x8 fbh = *(const bf16x8*)&sBh[wcol * 64 + j * 16 + lo][cq];
      bf16x8 fbl = *(const bf16x8*)&sBl[wcol * 64 + j * 16 + lo][cq];
#pragma unroll
      for (int i = 0; i < 4; ++i) {
        acc[i][j] = __builtin_amdgcn_mfma_f32_16x16x32_bf16(fah[i], fbh, acc[i][j], 0, 0, 0);
        acc[i][j] = __builtin_amdgcn_mfma_f32_16x16x32_bf16(fah[i], fbl, acc[i][j], 0, 0, 0);
        acc[i][j] = __builtin_amdgcn_mfma_f32_16x16x32_bf16(fal[i], fbh, acc[i][j], 0, 0, 0);
      }
    }
    __syncthreads();
  }

  // epilogue: e = exp(2c-2); fp64 row/col sums + candidates.
  // C/D layout: col = lo, row = quad*4 + reg  (m89/m91)
  double rowp[4][4];
  double colp[4];
#pragma unroll
  for (int i = 0; i < 4; ++i)
#pragma unroll
    for (int r = 0; r < 4; ++r) rowp[i][r] = 0.0;
#pragma unroll
  for (int j = 0; j < 4; ++j) colp[j] = 0.0;

#pragma unroll
  for (int i = 0; i < 4; ++i)
#pragma unroll
    for (int j = 0; j < 4; ++j)
#pragma unroll
      for (int r = 0; r < 4; ++r) {
        float c = acc[i][j][r];
        float e = __expf(2.f * c - 2.f);
        rowp[i][r] += (double)e;
        colp[j] += (double)e;
        if (c >= CAND_T0) {
          int row = rowBase + wrow * 64 + i * 16 + quad * 4 + r;
          int col = colBase + wcol * 64 + j * 16 + lo;
          int idx = atomicAdd(cnt, 1);
          if (idx < ncap) cand[idx] = ((u32)row << 13) | (u32)col;
        }
      }

#pragma unroll
  for (int i = 0; i < 4; ++i)
#pragma unroll
    for (int r = 0; r < 4; ++r) {
      double v = rowp[i][r];
#pragma unroll
      for (int off = 8; off; off >>= 1) v += __shfl_xor(v, off, 16);
      if (lo == 0) {
        int row = rowBase + wrow * 64 + i * 16 + quad * 4 + r;
        atomicAdd(&R[row], v);
      }
    }
#pragma unroll
  for (int j = 0; j < 4; ++j) {
    double v = colp[j];
    v += __shfl_xor(v, 16);
    v += __shfl_xor(v, 32);
    if (quad == 0) {
      int col = colBase + wcol * 64 + j * 16 + lo;
      atomicAdd(&C[col], v);
    }
  }
}

// ---------------- fp32 fallback GEMM (used only if ws too small) ----------------
__global__ __launch_bounds__(256) void k_gemm_f32(
    const float* __restrict__ A, const float* __restrict__ B,
    double* __restrict__ R, double* __restrict__ C,
    int* __restrict__ cnt, u32* __restrict__ cand, int ncap) {
  __shared__ float As[32][128];
  __shared__ float Bs[32][128];
  __shared__ double colLds[16][128];
  const int tid = threadIdx.x;
  const int tx = tid & 15, ty = tid >> 4;
  const int rowBase = blockIdx.y * 128;
  const int colBase = blockIdx.x * 128;
  float acc[8][8];
#pragma unroll
  for (int i = 0; i < 8; ++i)
#pragma unroll
    for (int j = 0; j < 8; ++j) acc[i][j] = 0.f;
  const int lr = tid >> 3;
  const int lc = (tid & 7) << 2;
  for (int kk = 0; kk < DD; kk += 32) {
#pragma unroll
    for (int r = 0; r < 4; ++r) {
      int row = lr + r * 32;
      float4 av = *(const float4*)(A + (size_t)(rowBase + row) * DD + kk + lc);
      float4 bv = *(const float4*)(B + (size_t)(colBase + row) * DD + kk + lc);
      As[lc + 0][row] = av.x; As[lc + 1][row] = av.y; As[lc + 2][row] = av.z; As[lc + 3][row] = av.w;
      Bs[lc + 0][row] = bv.x; Bs[lc + 1][row] = bv.y; Bs[lc + 2][row] = bv.z; Bs[lc + 3][row] = bv.w;
    }
    __syncthreads();
#pragma unroll 4
    for (int k = 0; k < 32; ++k) {
      float a[8], b[8];
      *(float4*)(a + 0) = *(const float4*)(&As[k][ty * 8 + 0]);
      *(float4*)(a + 4) = *(const float4*)(&As[k][ty * 8 + 4]);
      *(float4*)(b + 0) = *(const float4*)(&Bs[k][tx * 8 + 0]);
      *(float4*)(b + 4) = *(const float4*)(&Bs[k][tx * 8 + 4]);
#pragma unroll
      for (int i = 0; i < 8; ++i)
#pragma unroll
        for (int j = 0; j < 8; ++j)
          acc[i][j] = fmaf(a[i], b[j], acc[i][j]);
    }
    __syncthreads();
  }
  double colpart[8];
#pragma unroll
  for (int j = 0; j < 8; ++j) colpart[j] = 0.0;
#pragma unroll
  for (int i = 0; i < 8; ++i) {
    double rp = 0.0;
#pragma unroll
    for (int j = 0; j < 8; ++j) {
      float e = __expf(2.f * acc[i][j] - 2.f);
      rp += (double)e;
      colpart[j] += (double)e;
    }
#pragma unroll
    for (int off = 8; off; off >>= 1) rp += __shfl_down(rp, off, 16);
    if (tx == 0) atomicAdd(&R[rowBase + ty * 8 + i], rp);
  }
#pragma unroll
  for (int j = 0; j < 8; ++j) colLds[ty][tx * 8 + j] = colpart[j];
  __syncthreads();
  if (tid < 128) {
    double s = 0.0;
#pragma unroll
    for (int t = 0; t < 16; ++t) s += colLds[t][tid];
    atomicAdd(&C[colBase + tid], s);
  }
#pragma unroll
  for (int i = 0; i < 8; ++i)
#pragma unroll
    for (int j = 0; j < 8; ++j) {
      if (acc[i][j] >= CAND_T0) {
        int idx = atomicAdd(cnt, 1);
        if (idx < ncap)
          cand[idx] = ((u32)(rowBase + ty * 8 + i) << 13) | (u32)(colBase + tx * 8 + j);
      }
    }
}

// One wave per candidate: exact fp64 dot, fp64 score, orderable u64 key.
__global__ __launch_bounds__(256) void k_score(
    const float* __restrict__ A, const float* __restrict__ B,
    const double* __restrict__ R, const double* __restrict__ C,
    const int* __restrict__ cnt, const u32* __restrict__ cand,
    u64* __restrict__ keys, int ncap) {
  int w = (int)((blockIdx.x * 256 + threadIdx.x) >> 6);
  int lane = threadIdx.x & 63;
  int n = *cnt; if (n > ncap) n = ncap;
  if (w >= n) return;
  u32 mn = cand[w];
  int m = (int)(mn >> 13), nn = (int)(mn & 8191u);
  const float* ar = A + (size_t)m * DD;
  const float* br = B + (size_t)nn * DD;
  double s = 0.0;
#pragma unroll
  for (int d = 0; d < DD; d += 64)
    s = fma((double)ar[d + lane], (double)br[d + lane], s);
#pragma unroll
  for (int off = 32; off; off >>= 1) s += __shfl_down(s, off);
  if (lane == 0) {
    double sc = exp(4.0 * s - 4.0) / (R[m] * C[nn]);
    keys[w] = (u64)__double_as_longlong(sc);
  }
}

// Single-block LDS bitonic sort (key desc, flat-idx asc) -> top-256.
__global__ __launch_bounds__(1024) void k_sort(
    const int* __restrict__ cnt, const u32* __restrict__ cand,
    const u64* __restrict__ keys, float* __restrict__ out, int ncap) {
  extern __shared__ char smem[];
  u64* sk = (u64*)smem;
  u32* sm = (u32*)(smem + (size_t)NPAD * 8);
  const int tid = threadIdx.x;
  int m = *cnt; if (m > ncap) m = ncap; if (m > NPAD) m = NPAD;
  int np = KTOP; while (np < m) np <<= 1;

  for (int i = tid; i < np; i += 1024) { sk[i] = 0; sm[i] = 0xFFFFFFFFu; }
  __syncthreads();
  for (int i = tid; i < m; i += 1024) { sk[i] = keys[i]; sm[i] = cand[i]; }
  __syncthreads();

  for (unsigned k = 2; k <= (unsigned)np; k <<= 1) {
    for (unsigned j = k >> 1; j > 0; j >>= 1) {
      for (unsigned i = tid; i < (unsigned)np; i += 1024) {
        unsigned l = i ^ j;
        if (l > i) {
          u64 ki = sk[i], kl = sk[l];
          u32 mi = sm[i], ml = sm[l];
          bool dir = ((i & k) == 0);
          bool i_worse = (ki < kl) || (ki == kl && mi > ml);
          bool l_worse = (kl < ki) || (kl == ki && ml > mi);
          if (dir ? i_worse : l_worse) {
            sk[i] = kl; sk[l] = ki; sm[i] = ml; sm[l] = mi;
          }
        }
      }
      __syncthreads();
    }
  }

  for (int r = tid; r < KTOP; r += 1024) {
    u32 mn = sm[r];
    u64 kk = sk[r];
    out[r] = (float)(mn >> 13);
    out[KTOP + r] = (float)(mn & 8191u);
    out[2 * KTOP + r] = (float)__longlong_as_double((long long)kk);
  }
}

extern "C" void kernel_launch(void* const* d_in, const int* in_sizes, int n_in,
                              void* d_out, int out_size, void* d_ws, size_t ws_size,
                              hipStream_t stream) {
  (void)in_sizes; (void)n_in; (void)out_size;
  const float* A = (const float*)d_in[0];  // ref_feats [8192,256]
  const float* B = (const float*)d_in[1];  // src_feats [8192,256]
  float* out = (float*)d_out;
  char* ws = (char*)d_ws;
  double* R = (double*)(ws + OFF_R);
  double* C = (double*)(ws + OFF_C);
  int* cnt = (int*)(ws + OFF_CNT);
  u32* cand = (u32*)(ws + OFF_CAND);
  u64* keys = (u64*)(ws + OFF_KEYS);

  if (ws_size >= (size_t)WS_REQ) {
    u16* Ahp = (u16*)(ws + OFF_AH);
    u16* Alp = (u16*)(ws + OFF_AL);
    u16* Bhp = (u16*)(ws + OFF_BH);
    u16* Blp = (u16*)(ws + OFF_BL);
    hipLaunchKernelGGL(k_prep2, dim3(4096), dim3(256), 0, stream,
                       A, B, Ahp, Alp, Bhp, Blp, R, C, cnt);
    hipLaunchKernelGGL(k_gemm_mfma, dim3(4096), dim3(256), 0, stream,
                       Ahp, Alp, Bhp, Blp, R, C, cnt, cand, NCAP);
  } else {
    hipLaunchKernelGGL(k_init, dim3(32), dim3(256), 0, stream, R, C, cnt);
    hipLaunchKernelGGL(k_gemm_f32, dim3(ND / 128, MD / 128), dim3(256), 0, stream,
                       A, B, R, C, cnt, cand, NCAP);
  }

  hipLaunchKernelGGL(k_score, dim3(NCAP / 4), dim3(256), 0, stream,
                     A, B, R, C, cnt, cand, keys, NCAP);
  hipLaunchKernelGGL(k_sort, dim3(1), dim3(1024), (size_t)NPAD * 12, stream,
                     cnt, cand, keys, out, NCAP);
}

// Round 7
// 204.153 us; speedup vs baseline: 1.6978x; 1.1334x over previous
//
#include <hip/hip_runtime.h>

#define MD 8192
#define ND 8192
#define DD 256
#define KTOP 256
#define CAND_T0 0.25f
#define NCAP 4096
#define NPAD 4096

typedef unsigned int u32;
typedef unsigned short u16;
typedef unsigned long long u64;

// workspace layout (bytes)
#define OFF_R    0                 // double R[8192]   64 KB
#define OFF_C    65536             // double C[8192]   64 KB
#define OFF_CNT  131072            // int
#define OFF_CAND 131200            // u32 cand[4096]   16 KB
#define OFF_KEYS 163840            // u64 keys[4096]   32 KB
#define OFF_AH   262144            // u16 Ah[8192*256]  4 MB
#define OFF_AL   (OFF_AH + 4194304)
#define OFF_BH   (OFF_AL + 4194304)
#define OFF_BL   (OFF_BH + 4194304)
#define WS_REQ   (OFF_BL + 4194304)

using bf16x8 = __attribute__((ext_vector_type(8))) __bf16;
using f32x4  = __attribute__((ext_vector_type(4))) float;

#define AS1 __attribute__((address_space(1)))
#define AS3 __attribute__((address_space(3)))

__device__ __forceinline__ u16 f2bf(float x) {
  union { float f; u32 u; } v; v.f = x;
  u32 r = v.u + 0x7fffu + ((v.u >> 16) & 1u);   // RNE
  return (u16)(r >> 16);
}
__device__ __forceinline__ float bf2f(u16 h) {
  union { float f; u32 u; } v; v.u = ((u32)h) << 16;
  return v.f;
}

__global__ void k_init(double* __restrict__ R, double* __restrict__ C, int* __restrict__ cnt) {
  int i = blockIdx.x * blockDim.x + threadIdx.x;
  if (i < MD) R[i] = 0.0;
  if (i < ND) C[i] = 0.0;
  if (i == 0) *cnt = 0;
}

// Fused: zero R/C/cnt + split both matrices into (hi, lo) bf16 planes.
__global__ __launch_bounds__(256) void k_prep2(
    const float* __restrict__ A, const float* __restrict__ B,
    u16* __restrict__ Ahp, u16* __restrict__ Alp,
    u16* __restrict__ Bhp, u16* __restrict__ Blp,
    double* __restrict__ R, double* __restrict__ C, int* __restrict__ cnt) {
  const int b = blockIdx.x, tid = threadIdx.x;
  const int gid = b * 256 + tid;
  if (gid < MD) R[gid] = 0.0;
  else if (gid < MD + ND) C[gid - MD] = 0.0;
  if (gid == 0) *cnt = 0;

  const float* X; u16 *hp, *lp; int i;
  if (b < 2048) { X = A; hp = Ahp; lp = Alp; i = gid; }
  else          { X = B; hp = Bhp; lp = Blp; i = gid - 2048 * 256; }
  float4 v = ((const float4*)X)[i];
  ushort4 h, l;
  h.x = f2bf(v.x); l.x = f2bf(v.x - bf2f(h.x));
  h.y = f2bf(v.y); l.y = f2bf(v.y - bf2f(h.y));
  h.z = f2bf(v.z); l.z = f2bf(v.z - bf2f(h.z));
  h.w = f2bf(v.w); l.w = f2bf(v.w - bf2f(h.w));
  ((ushort4*)hp)[i] = h;
  ((ushort4*)lp)[i] = l;
}

// ---------------- MFMA split-bf16 GEMM ----------------
// 128x128 tile, BK=32, 4 waves each 64x64 (4x4 tiles of 16x16).
// c = ah*bh + ah*bl + al*bh, fp32 MFMA accumulate.
// XOR chunk swizzle: LDS conflict-free (R5: SQ_LDS_BANK_CONFLICT = 0).
// XCD swizzle for L2 locality (R6: HBM-visible staging well fed).
// __launch_bounds__(256,3): 170 regs/lane -> working set (~134) fits,
// no scratch spill (R6's (256,4) spilled ~94 MB/dispatch), occupancy
// stays at the measured 3 blocks/CU.
__global__ __launch_bounds__(256, 3) void k_gemm_mfma(
    const u16* __restrict__ Ah, const u16* __restrict__ Al,
    const u16* __restrict__ Bh, const u16* __restrict__ Bl,
    double* __restrict__ R, double* __restrict__ C,
    int* __restrict__ cnt, u32* __restrict__ cand, int ncap) {
  __shared__ u16 sAh[128][32];
  __shared__ u16 sAl[128][32];
  __shared__ u16 sBh[128][32];
  __shared__ u16 sBl[128][32];

  const int tid = threadIdx.x;
  const int lane = tid & 63;
  const int wid = tid >> 6;           // 0..3
  const int wrow = wid >> 1, wcol = wid & 1;

  // XCD-aware block swizzle (1-D grid of 4096)
  const int g = blockIdx.x;
  const int xcd = g & 7;
  const int l = g >> 3;               // 0..511
  const int rowTile = xcd * 8 + (l & 7);
  const int colTile = l >> 3;
  const int rowBase = rowTile * 128;
  const int colBase = colTile * 128;

  const int quad = lane >> 4, lo = lane & 15;
  const int sw = (lo >> 1) & 3;
  const int cswz = (lane & 3) ^ ((lane >> 3) & 3);

  u16* lb;
  const u16* gb;
  if (wid == 0)      { lb = &sAh[0][0]; gb = Ah + (size_t)rowBase * DD; }
  else if (wid == 1) { lb = &sAl[0][0]; gb = Al + (size_t)rowBase * DD; }
  else if (wid == 2) { lb = &sBh[0][0]; gb = Bh + (size_t)colBase * DD; }
  else               { lb = &sBl[0][0]; gb = Bl + (size_t)colBase * DD; }

  f32x4 acc[4][4];
#pragma unroll
  for (int i = 0; i < 4; ++i)
#pragma unroll
    for (int j = 0; j < 4; ++j) acc[i][j] = (f32x4){0.f, 0.f, 0.f, 0.f};

  for (int kt = 0; kt < 8; ++kt) {
    const int kk = kt * 32;
#pragma unroll
    for (int ch = 0; ch < 8; ++ch) {
      const u16* gp = gb + (size_t)(ch * 16 + (lane >> 2)) * DD + kk + cswz * 8;
      __builtin_amdgcn_global_load_lds((const AS1 void*)gp, (AS3 void*)(lb + ch * 512), 16, 0, 0);
    }
    __syncthreads();

    const int cq = (quad ^ sw) * 8;
    bf16x8 fah[4], fal[4];
#pragma unroll
    for (int t = 0; t < 4; ++t) {
      fah[t] = *(const bf16x8*)&sAh[wrow * 64 + t * 16 + lo][cq];
      fal[t] = *(const bf16x8*)&sAl[wrow * 64 + t * 16 + lo][cq];
    }
#pragma unroll
    for (int j = 0; j < 4; ++j) {
      bf16x8 fbh = *(const bf16x8*)&sBh[wcol * 64 + j * 16 + lo][cq];
      bf16x8 fbl = *(const bf16x8*)&sBl[wcol * 64 + j * 16 + lo][cq];
#pragma unroll
      for (int i = 0; i < 4; ++i) {
        acc[i][j] = __builtin_amdgcn_mfma_f32_16x16x32_bf16(fah[i], fbh, acc[i][j], 0, 0, 0);
        acc[i][j] = __builtin_amdgcn_mfma_f32_16x16x32_bf16(fah[i], fbl, acc[i][j], 0, 0, 0);
        acc[i][j] = __builtin_amdgcn_mfma_f32_16x16x32_bf16(fal[i], fbh, acc[i][j], 0, 0, 0);
      }
    }
    __syncthreads();
  }

  // epilogue: e = exp(2c-2); fp64 row/col sums + candidates.
  // C/D layout: col = lo, row = quad*4 + reg  (m89/m91)
  double rowp[4][4];
  double colp[4];
#pragma unroll
  for (int i = 0; i < 4; ++i)
#pragma unroll
    for (int r = 0; r < 4; ++r) rowp[i][r] = 0.0;
#pragma unroll
  for (int j = 0; j < 4; ++j) colp[j] = 0.0;

#pragma unroll
  for (int i = 0; i < 4; ++i)
#pragma unroll
    for (int j = 0; j < 4; ++j)
#pragma unroll
      for (int r = 0; r < 4; ++r) {
        float c = acc[i][j][r];
        float e = __expf(2.f * c - 2.f);
        rowp[i][r] += (double)e;
        colp[j] += (double)e;
        if (c >= CAND_T0) {
          int row = rowBase + wrow * 64 + i * 16 + quad * 4 + r;
          int col = colBase + wcol * 64 + j * 16 + lo;
          int idx = atomicAdd(cnt, 1);
          if (idx < ncap) cand[idx] = ((u32)row << 13) | (u32)col;
        }
      }

#pragma unroll
  for (int i = 0; i < 4; ++i)
#pragma unroll
    for (int r = 0; r < 4; ++r) {
      double v = rowp[i][r];
#pragma unroll
      for (int off = 8; off; off >>= 1) v += __shfl_xor(v, off, 16);
      if (lo == 0) {
        int row = rowBase + wrow * 64 + i * 16 + quad * 4 + r;
        atomicAdd(&R[row], v);
      }
    }
#pragma unroll
  for (int j = 0; j < 4; ++j) {
    double v = colp[j];
    v += __shfl_xor(v, 16);
    v += __shfl_xor(v, 32);
    if (quad == 0) {
      int col = colBase + wcol * 64 + j * 16 + lo;
      atomicAdd(&C[col], v);
    }
  }
}

// ---------------- fp32 fallback GEMM (used only if ws too small) ----------------
__global__ __launch_bounds__(256) void k_gemm_f32(
    const float* __restrict__ A, const float* __restrict__ B,
    double* __restrict__ R, double* __restrict__ C,
    int* __restrict__ cnt, u32* __restrict__ cand, int ncap) {
  __shared__ float As[32][128];
  __shared__ float Bs[32][128];
  __shared__ double colLds[16][128];
  const int tid = threadIdx.x;
  const int tx = tid & 15, ty = tid >> 4;
  const int rowBase = blockIdx.y * 128;
  const int colBase = blockIdx.x * 128;
  float acc[8][8];
#pragma unroll
  for (int i = 0; i < 8; ++i)
#pragma unroll
    for (int j = 0; j < 8; ++j) acc[i][j] = 0.f;
  const int lr = tid >> 3;
  const int lc = (tid & 7) << 2;
  for (int kk = 0; kk < DD; kk += 32) {
#pragma unroll
    for (int r = 0; r < 4; ++r) {
      int row = lr + r * 32;
      float4 av = *(const float4*)(A + (size_t)(rowBase + row) * DD + kk + lc);
      float4 bv = *(const float4*)(B + (size_t)(colBase + row) * DD + kk + lc);
      As[lc + 0][row] = av.x; As[lc + 1][row] = av.y; As[lc + 2][row] = av.z; As[lc + 3][row] = av.w;
      Bs[lc + 0][row] = bv.x; Bs[lc + 1][row] = bv.y; Bs[lc + 2][row] = bv.z; Bs[lc + 3][row] = bv.w;
    }
    __syncthreads();
#pragma unroll 4
    for (int k = 0; k < 32; ++k) {
      float a[8], b[8];
      *(float4*)(a + 0) = *(const float4*)(&As[k][ty * 8 + 0]);
      *(float4*)(a + 4) = *(const float4*)(&As[k][ty * 8 + 4]);
      *(float4*)(b + 0) = *(const float4*)(&Bs[k][tx * 8 + 0]);
      *(float4*)(b + 4) = *(const float4*)(&Bs[k][tx * 8 + 4]);
#pragma unroll
      for (int i = 0; i < 8; ++i)
#pragma unroll
        for (int j = 0; j < 8; ++j)
          acc[i][j] = fmaf(a[i], b[j], acc[i][j]);
    }
    __syncthreads();
  }
  double colpart[8];
#pragma unroll
  for (int j = 0; j < 8; ++j) colpart[j] = 0.0;
#pragma unroll
  for (int i = 0; i < 8; ++i) {
    double rp = 0.0;
#pragma unroll
    for (int j = 0; j < 8; ++j) {
      float e = __expf(2.f * acc[i][j] - 2.f);
      rp += (double)e;
      colpart[j] += (double)e;
    }
#pragma unroll
    for (int off = 8; off; off >>= 1) rp += __shfl_down(rp, off, 16);
    if (tx == 0) atomicAdd(&R[rowBase + ty * 8 + i], rp);
  }
#pragma unroll
  for (int j = 0; j < 8; ++j) colLds[ty][tx * 8 + j] = colpart[j];
  __syncthreads();
  if (tid < 128) {
    double s = 0.0;
#pragma unroll
    for (int t = 0; t < 16; ++t) s += colLds[t][tid];
    atomicAdd(&C[colBase + tid], s);
  }
#pragma unroll
  for (int i = 0; i < 8; ++i)
#pragma unroll
    for (int j = 0; j < 8; ++j) {
      if (acc[i][j] >= CAND_T0) {
        int idx = atomicAdd(cnt, 1);
        if (idx < ncap)
          cand[idx] = ((u32)(rowBase + ty * 8 + i) << 13) | (u32)(colBase + tx * 8 + j);
      }
    }
}

// One wave per candidate: exact fp64 dot, fp64 score, orderable u64 key.
__global__ __launch_bounds__(256) void k_score(
    const float* __restrict__ A, const float* __restrict__ B,
    const double* __restrict__ R, const double* __restrict__ C,
    const int* __restrict__ cnt, const u32* __restrict__ cand,
    u64* __restrict__ keys, int ncap) {
  int w = (int)((blockIdx.x * 256 + threadIdx.x) >> 6);
  int lane = threadIdx.x & 63;
  int n = *cnt; if (n > ncap) n = ncap;
  if (w >= n) return;
  u32 mn = cand[w];
  int m = (int)(mn >> 13), nn = (int)(mn & 8191u);
  const float* ar = A + (size_t)m * DD;
  const float* br = B + (size_t)nn * DD;
  double s = 0.0;
#pragma unroll
  for (int d = 0; d < DD; d += 64)
    s = fma((double)ar[d + lane], (double)br[d + lane], s);
#pragma unroll
  for (int off = 32; off; off >>= 1) s += __shfl_down(s, off);
  if (lane == 0) {
    double sc = exp(4.0 * s - 4.0) / (R[m] * C[nn]);
    keys[w] = (u64)__double_as_longlong(sc);
  }
}

// (key desc, flat-idx asc) strict order; idx unique so no true ties.
__device__ __forceinline__ bool is_worse(u64 ka, u32 ma, u64 kb, u32 mb) {
  return (ka < kb) || (ka == kb && ma > mb);
}

// Single-block top-256: register/shuffle bitonic.
// Fast path (cnt <= 2048): each wave sorts a 128-elem segment in registers
// (zero barriers), merge stages use LDS only for j>=128 (10 barrier stages),
// j<=64 per-wave in registers. Legacy 4096 LDS bitonic as fallback.
__global__ __launch_bounds__(1024) void k_sort(
    const int* __restrict__ cnt, const u32* __restrict__ cand,
    const u64* __restrict__ keys, float* __restrict__ out, int ncap) {
  extern __shared__ char smem[];
  u64* sk = (u64*)smem;
  u32* sm = (u32*)(smem + (size_t)NPAD * 8);
  const int tid = threadIdx.x;
  const int lane = tid & 63;
  const int wid = tid >> 6;
  int m = *cnt; if (m > ncap) m = ncap;

  if (m <= 2048) {
    const int NP = 2048;
    const int base = wid * 128;
    const int i0 = base + lane * 2;

    // phase 1: wave-local sort of 128-elem segment, direct from global
    u64 k0 = (i0 < m) ? keys[i0] : 0;
    u64 k1 = (i0 + 1 < m) ? keys[i0 + 1] : 0;
    u32 m0 = (i0 < m) ? cand[i0] : 0xFFFFFFFFu;
    u32 m1 = (i0 + 1 < m) ? cand[i0 + 1] : 0xFFFFFFFFu;
#pragma unroll
    for (int k = 2; k <= 128; k <<= 1) {
#pragma unroll
      for (int j = k >> 1; j >= 1; j >>= 1) {
        const bool bf = ((i0 & k) == 0);
        if (j == 1) {
          bool sw = bf ? is_worse(k0, m0, k1, m1) : is_worse(k1, m1, k0, m0);
          if (sw) { u64 tk = k0; k0 = k1; k1 = tk; u32 tm = m0; m0 = m1; m1 = tm; }
        } else {
          const int j2 = j >> 1;
          const bool keepb = (bf == ((lane & j2) == 0));
          u64 pk0 = __shfl_xor(k0, j2); u32 pm0 = __shfl_xor(m0, j2);
          u64 pk1 = __shfl_xor(k1, j2); u32 pm1 = __shfl_xor(m1, j2);
          if (keepb == is_worse(k0, m0, pk0, pm0)) { k0 = pk0; m0 = pm0; }
          if (keepb == is_worse(k1, m1, pk1, pm1)) { k1 = pk1; m1 = pm1; }
        }
      }
    }
    sk[i0] = k0; sk[i0 + 1] = k1; sm[i0] = m0; sm[i0 + 1] = m1;
    __syncthreads();

    // phase 2: bitonic merges k=256..2048
    for (int k = 256; k <= NP; k <<= 1) {
      for (int j = k >> 1; j >= 128; j >>= 1) {
        for (int i = tid; i < NP; i += 1024) {
          int l = i ^ j;
          if (l > i) {
            u64 ki = sk[i], kl = sk[l];
            u32 mi = sm[i], ml = sm[l];
            bool bf = ((i & k) == 0);
            bool swp = bf ? is_worse(ki, mi, kl, ml) : is_worse(kl, ml, ki, mi);
            if (swp) { sk[i] = kl; sk[l] = ki; sm[i] = ml; sm[l] = mi; }
          }
        }
        __syncthreads();
      }
      // register stages j=64..1 (direction constant per 128-segment: k>=256)
      k0 = sk[i0]; k1 = sk[i0 + 1]; m0 = sm[i0]; m1 = sm[i0 + 1];
      const bool bf = ((base & k) == 0);
#pragma unroll
      for (int j = 64; j >= 2; j >>= 1) {
        const int j2 = j >> 1;
        const bool keepb = (bf == ((lane & j2) == 0));
        u64 pk0 = __shfl_xor(k0, j2); u32 pm0 = __shfl_xor(m0, j2);
        u64 pk1 = __shfl_xor(k1, j2); u32 pm1 = __shfl_xor(m1, j2);
        if (keepb == is_worse(k0, m0, pk0, pm0)) { k0 = pk0; m0 = pm0; }
        if (keepb == is_worse(k1, m1, pk1, pm1)) { k1 = pk1; m1 = pm1; }
      }
      {
        bool sw = bf ? is_worse(k0, m0, k1, m1) : is_worse(k1, m1, k0, m0);
        if (sw) { u64 tk = k0; k0 = k1; k1 = tk; u32 tm = m0; m0 = m1; m1 = tm; }
      }
      sk[i0] = k0; sk[i0 + 1] = k1; sm[i0] = m0; sm[i0 + 1] = m1;
      __syncthreads();
    }
  } else {
    // legacy: full 4096 LDS bitonic
    const int np = NPAD;
    for (int i = tid; i < np; i += 1024) { sk[i] = 0; sm[i] = 0xFFFFFFFFu; }
    __syncthreads();
    for (int i = tid; i < m; i += 1024) { sk[i] = keys[i]; sm[i] = cand[i]; }
    __syncthreads();
    for (unsigned k = 2; k <= (unsigned)np; k <<= 1) {
      for (unsigned j = k >> 1; j > 0; j >>= 1) {
        for (unsigned i = tid; i < (unsigned)np; i += 1024) {
          unsigned l = i ^ j;
          if (l > i) {
            u64 ki = sk[i], kl = sk[l];
            u32 mi = sm[i], ml = sm[l];
            bool dir = ((i & k) == 0);
            bool swp = dir ? is_worse(ki, mi, kl, ml) : is_worse(kl, ml, ki, mi);
            if (swp) { sk[i] = kl; sk[l] = ki; sm[i] = ml; sm[l] = mi; }
          }
        }
        __syncthreads();
      }
    }
  }

  for (int r = tid; r < KTOP; r += 1024) {
    u32 mn = sm[r];
    u64 kk = sk[r];
    out[r] = (float)(mn >> 13);
    out[KTOP + r] = (float)(mn & 8191u);
    out[2 * KTOP + r] = (float)__longlong_as_double((long long)kk);
  }
}

extern "C" void kernel_launch(void* const* d_in, const int* in_sizes, int n_in,
                              void* d_out, int out_size, void* d_ws, size_t ws_size,
                              hipStream_t stream) {
  (void)in_sizes; (void)n_in; (void)out_size;
  const float* A = (const float*)d_in[0];  // ref_feats [8192,256]
  const float* B = (const float*)d_in[1];  // src_feats [8192,256]
  float* out = (float*)d_out;
  char* ws = (char*)d_ws;
  double* R = (double*)(ws + OFF_R);
  double* C = (double*)(ws + OFF_C);
  int* cnt = (int*)(ws + OFF_CNT);
  u32* cand = (u32*)(ws + OFF_CAND);
  u64* keys = (u64*)(ws + OFF_KEYS);

  if (ws_size >= (size_t)WS_REQ) {
    u16* Ahp = (u16*)(ws + OFF_AH);
    u16* Alp = (u16*)(ws + OFF_AL);
    u16* Bhp = (u16*)(ws + OFF_BH);
    u16* Blp = (u16*)(ws + OFF_BL);
    hipLaunchKernelGGL(k_prep2, dim3(4096), dim3(256), 0, stream,
                       A, B, Ahp, Alp, Bhp, Blp, R, C, cnt);
    hipLaunchKernelGGL(k_gemm_mfma, dim3(4096), dim3(256), 0, stream,
                       Ahp, Alp, Bhp, Blp, R, C, cnt, cand, NCAP);
  } else {
    hipLaunchKernelGGL(k_init, dim3(32), dim3(256), 0, stream, R, C, cnt);
    hipLaunchKernelGGL(k_gemm_f32, dim3(ND / 128, MD / 128), dim3(256), 0, stream,
                       A, B, R, C, cnt, cand, NCAP);
  }

  hipLaunchKernelGGL(k_score, dim3(NCAP / 4), dim3(256), 0, stream,
                     A, B, R, C, cnt, cand, keys, NCAP);
  hipLaunchKernelGGL(k_sort, dim3(1), dim3(1024), (size_t)NPAD * 12, stream,
                     cnt, cand, keys, out, NCAP);
}

// Round 8
// 199.991 us; speedup vs baseline: 1.7331x; 1.0208x over previous
//
#include <hip/hip_runtime.h>

#define MD 8192
#define ND 8192
#define DD 256
#define KTOP 256
#define CAND_T0 0.26f
#define NCAP 4096
#define NPAD 4096

typedef unsigned int u32;
typedef unsigned short u16;
typedef unsigned long long u64;

// workspace layout (bytes)
#define OFF_R    0                  // double R[8192]          64 KB
#define OFF_CP   65536              // double CP[8][8192]     512 KB (per-XCD-group col partials)
#define OFF_CNT  589824             // int
#define OFF_CAND 589952             // u32 cand[4096]          16 KB
#define OFF_KEYS 606336             // u64 keys[4096]          32 KB
#define OFF_AH   655360             // u16 Ah[8192*256]         4 MB
#define OFF_AL   (OFF_AH + 4194304)
#define OFF_BH   (OFF_AL + 4194304)
#define OFF_BL   (OFF_BH + 4194304)
#define WS_REQ   (OFF_BL + 4194304)

using bf16x8 = __attribute__((ext_vector_type(8))) __bf16;
using f32x4  = __attribute__((ext_vector_type(4))) float;

#define AS1 __attribute__((address_space(1)))
#define AS3 __attribute__((address_space(3)))

__device__ __forceinline__ u16 f2bf(float x) {
  union { float f; u32 u; } v; v.f = x;
  u32 r = v.u + 0x7fffu + ((v.u >> 16) & 1u);   // RNE
  return (u16)(r >> 16);
}
__device__ __forceinline__ float bf2f(u16 h) {
  union { float f; u32 u; } v; v.u = ((u32)h) << 16;
  return v.f;
}

// fallback-path init: zero R, CP, cnt (grid-stride)
__global__ void k_init(double* __restrict__ R, double* __restrict__ CP, int* __restrict__ cnt) {
  int stride = gridDim.x * blockDim.x;
  for (int i = blockIdx.x * blockDim.x + threadIdx.x; i < MD + 8 * ND; i += stride) {
    if (i < MD) R[i] = 0.0;
    else CP[i - MD] = 0.0;
  }
  if (blockIdx.x == 0 && threadIdx.x == 0) *cnt = 0;
}

// Fused: zero R/CP/cnt + split both matrices into (hi, lo) bf16 planes.
__global__ __launch_bounds__(256) void k_prep2(
    const float* __restrict__ A, const float* __restrict__ B,
    u16* __restrict__ Ahp, u16* __restrict__ Alp,
    u16* __restrict__ Bhp, u16* __restrict__ Blp,
    double* __restrict__ R, double* __restrict__ CP, int* __restrict__ cnt) {
  const int b = blockIdx.x, tid = threadIdx.x;
  const int gid = b * 256 + tid;
  if (gid < MD) R[gid] = 0.0;
  else if (gid < MD + 8 * ND) CP[gid - MD] = 0.0;
  if (gid == 0) *cnt = 0;

  const float* X; u16 *hp, *lp; int i;
  if (b < 2048) { X = A; hp = Ahp; lp = Alp; i = gid; }
  else          { X = B; hp = Bhp; lp = Blp; i = gid - 2048 * 256; }
  float4 v = ((const float4*)X)[i];
  ushort4 h, l;
  h.x = f2bf(v.x); l.x = f2bf(v.x - bf2f(h.x));
  h.y = f2bf(v.y); l.y = f2bf(v.y - bf2f(h.y));
  h.z = f2bf(v.z); l.z = f2bf(v.z - bf2f(h.z));
  h.w = f2bf(v.w); l.w = f2bf(v.w - bf2f(h.w));
  ((ushort4*)hp)[i] = h;
  ((ushort4*)lp)[i] = l;
}

// ---------------- MFMA split-bf16 GEMM ----------------
// 128x128 tile, BK=32, 4 waves each 64x64 (4x4 tiles of 16x16).
// c = ah*bh + ah*bl + al*bh, fp32 MFMA accumulate.
// XOR chunk swizzle: LDS conflict-free (R5: SQ_LDS_BANK_CONFLICT = 0).
// XCD swizzle: g&7 groups share a row-panel -> R atomics group-local.
// C atomics partitioned into CP[g&7][...] to kill cross-XCD line ping-pong
// (R7: 41 MB WRITE_SIZE ~= C-line coherence traffic).
__global__ __launch_bounds__(256, 3) void k_gemm_mfma(
    const u16* __restrict__ Ah, const u16* __restrict__ Al,
    const u16* __restrict__ Bh, const u16* __restrict__ Bl,
    double* __restrict__ R, double* __restrict__ CP,
    int* __restrict__ cnt, u32* __restrict__ cand, int ncap) {
  __shared__ u16 sAh[128][32];
  __shared__ u16 sAl[128][32];
  __shared__ u16 sBh[128][32];
  __shared__ u16 sBl[128][32];

  const int tid = threadIdx.x;
  const int lane = tid & 63;
  const int wid = tid >> 6;           // 0..3
  const int wrow = wid >> 1, wcol = wid & 1;

  // XCD-aware block swizzle (1-D grid of 4096)
  const int g = blockIdx.x;
  const int xcd = g & 7;
  const int l = g >> 3;               // 0..511
  const int rowTile = xcd * 8 + (l & 7);
  const int colTile = l >> 3;
  const int rowBase = rowTile * 128;
  const int colBase = colTile * 128;
  double* Cmy = CP + (size_t)xcd * ND;

  const int quad = lane >> 4, lo = lane & 15;
  const int sw = (lo >> 1) & 3;
  const int cswz = (lane & 3) ^ ((lane >> 3) & 3);

  u16* lb;
  const u16* gb;
  if (wid == 0)      { lb = &sAh[0][0]; gb = Ah + (size_t)rowBase * DD; }
  else if (wid == 1) { lb = &sAl[0][0]; gb = Al + (size_t)rowBase * DD; }
  else if (wid == 2) { lb = &sBh[0][0]; gb = Bh + (size_t)colBase * DD; }
  else               { lb = &sBl[0][0]; gb = Bl + (size_t)colBase * DD; }

  f32x4 acc[4][4];
#pragma unroll
  for (int i = 0; i < 4; ++i)
#pragma unroll
    for (int j = 0; j < 4; ++j) acc[i][j] = (f32x4){0.f, 0.f, 0.f, 0.f};

  for (int kt = 0; kt < 8; ++kt) {
    const int kk = kt * 32;
#pragma unroll
    for (int ch = 0; ch < 8; ++ch) {
      const u16* gp = gb + (size_t)(ch * 16 + (lane >> 2)) * DD + kk + cswz * 8;
      __builtin_amdgcn_global_load_lds((const AS1 void*)gp, (AS3 void*)(lb + ch * 512), 16, 0, 0);
    }
    __syncthreads();

    const int cq = (quad ^ sw) * 8;
    bf16x8 fah[4], fal[4];
#pragma unroll
    for (int t = 0; t < 4; ++t) {
      fah[t] = *(const bf16x8*)&sAh[wrow * 64 + t * 16 + lo][cq];
      fal[t] = *(const bf16x8*)&sAl[wrow * 64 + t * 16 + lo][cq];
    }
#pragma unroll
    for (int j = 0; j < 4; ++j) {
      bf16x8 fbh = *(const bf16x8*)&sBh[wcol * 64 + j * 16 + lo][cq];
      bf16x8 fbl = *(const bf16x8*)&sBl[wcol * 64 + j * 16 + lo][cq];
#pragma unroll
      for (int i = 0; i < 4; ++i) {
        acc[i][j] = __builtin_amdgcn_mfma_f32_16x16x32_bf16(fah[i], fbh, acc[i][j], 0, 0, 0);
        acc[i][j] = __builtin_amdgcn_mfma_f32_16x16x32_bf16(fah[i], fbl, acc[i][j], 0, 0, 0);
        acc[i][j] = __builtin_amdgcn_mfma_f32_16x16x32_bf16(fal[i], fbh, acc[i][j], 0, 0, 0);
      }
    }
    __syncthreads();
  }

  // epilogue: e = exp(2c-2); row partials fp32 (pairwise-safe, ~1e-8 final
  // rel err after /sqrt(64) averaging), col partials fp64; candidates.
  // C/D layout: col = lo, row = quad*4 + reg  (m89/m91)
  float rowp[4][4];
  double colp[4];
#pragma unroll
  for (int i = 0; i < 4; ++i)
#pragma unroll
    for (int r = 0; r < 4; ++r) rowp[i][r] = 0.f;
#pragma unroll
  for (int j = 0; j < 4; ++j) colp[j] = 0.0;

#pragma unroll
  for (int i = 0; i < 4; ++i)
#pragma unroll
    for (int j = 0; j < 4; ++j)
#pragma unroll
      for (int r = 0; r < 4; ++r) {
        float c = acc[i][j][r];
        float e = __expf(2.f * c - 2.f);
        rowp[i][r] += e;
        colp[j] += (double)e;
        if (c >= CAND_T0) {
          int row = rowBase + wrow * 64 + i * 16 + quad * 4 + r;
          int col = colBase + wcol * 64 + j * 16 + lo;
          int idx = atomicAdd(cnt, 1);
          if (idx < ncap) cand[idx] = ((u32)row << 13) | (u32)col;
        }
      }

#pragma unroll
  for (int i = 0; i < 4; ++i)
#pragma unroll
    for (int r = 0; r < 4; ++r) {
      float v = rowp[i][r];
#pragma unroll
      for (int off = 8; off; off >>= 1) v += __shfl_xor(v, off, 16);
      if (lo == 0) {
        int row = rowBase + wrow * 64 + i * 16 + quad * 4 + r;
        atomicAdd(&R[row], (double)v);
      }
    }
#pragma unroll
  for (int j = 0; j < 4; ++j) {
    double v = colp[j];
    v += __shfl_xor(v, 16);
    v += __shfl_xor(v, 32);
    if (quad == 0) {
      int col = colBase + wcol * 64 + j * 16 + lo;
      atomicAdd(&Cmy[col], v);
    }
  }
}

// ---------------- fp32 fallback GEMM (used only if ws too small) ----------------
__global__ __launch_bounds__(256) void k_gemm_f32(
    const float* __restrict__ A, const float* __restrict__ B,
    double* __restrict__ R, double* __restrict__ CP,
    int* __restrict__ cnt, u32* __restrict__ cand, int ncap) {
  __shared__ float As[32][128];
  __shared__ float Bs[32][128];
  __shared__ double colLds[16][128];
  const int tid = threadIdx.x;
  const int tx = tid & 15, ty = tid >> 4;
  const int rowBase = blockIdx.y * 128;
  const int colBase = blockIdx.x * 128;
  float acc[8][8];
#pragma unroll
  for (int i = 0; i < 8; ++i)
#pragma unroll
    for (int j = 0; j < 8; ++j) acc[i][j] = 0.f;
  const int lr = tid >> 3;
  const int lc = (tid & 7) << 2;
  for (int kk = 0; kk < DD; kk += 32) {
#pragma unroll
    for (int r = 0; r < 4; ++r) {
      int row = lr + r * 32;
      float4 av = *(const float4*)(A + (size_t)(rowBase + row) * DD + kk + lc);
      float4 bv = *(const float4*)(B + (size_t)(colBase + row) * DD + kk + lc);
      As[lc + 0][row] = av.x; As[lc + 1][row] = av.y; As[lc + 2][row] = av.z; As[lc + 3][row] = av.w;
      Bs[lc + 0][row] = bv.x; Bs[lc + 1][row] = bv.y; Bs[lc + 2][row] = bv.z; Bs[lc + 3][row] = bv.w;
    }
    __syncthreads();
#pragma unroll 4
    for (int k = 0; k < 32; ++k) {
      float a[8], b[8];
      *(float4*)(a + 0) = *(const float4*)(&As[k][ty * 8 + 0]);
      *(float4*)(a + 4) = *(const float4*)(&As[k][ty * 8 + 4]);
      *(float4*)(b + 0) = *(const float4*)(&Bs[k][tx * 8 + 0]);
      *(float4*)(b + 4) = *(const float4*)(&Bs[k][tx * 8 + 4]);
#pragma unroll
      for (int i = 0; i < 8; ++i)
#pragma unroll
        for (int j = 0; j < 8; ++j)
          acc[i][j] = fmaf(a[i], b[j], acc[i][j]);
    }
    __syncthreads();
  }
  double colpart[8];
#pragma unroll
  for (int j = 0; j < 8; ++j) colpart[j] = 0.0;
#pragma unroll
  for (int i = 0; i < 8; ++i) {
    double rp = 0.0;
#pragma unroll
    for (int j = 0; j < 8; ++j) {
      float e = __expf(2.f * acc[i][j] - 2.f);
      rp += (double)e;
      colpart[j] += (double)e;
    }
#pragma unroll
    for (int off = 8; off; off >>= 1) rp += __shfl_down(rp, off, 16);
    if (tx == 0) atomicAdd(&R[rowBase + ty * 8 + i], rp);
  }
#pragma unroll
  for (int j = 0; j < 8; ++j) colLds[ty][tx * 8 + j] = colpart[j];
  __syncthreads();
  if (tid < 128) {
    double s = 0.0;
#pragma unroll
    for (int t = 0; t < 16; ++t) s += colLds[t][tid];
    atomicAdd(&CP[colBase + tid], s);   // partition 0 only
  }
#pragma unroll
  for (int i = 0; i < 8; ++i)
#pragma unroll
    for (int j = 0; j < 8; ++j) {
      if (acc[i][j] >= CAND_T0) {
        int idx = atomicAdd(cnt, 1);
        if (idx < ncap)
          cand[idx] = ((u32)(rowBase + ty * 8 + i) << 13) | (u32)(colBase + tx * 8 + j);
      }
    }
}

// One wave per candidate: exact fp64 dot, fp64 score, orderable u64 key.
__global__ __launch_bounds__(256) void k_score(
    const float* __restrict__ A, const float* __restrict__ B,
    const double* __restrict__ R, const double* __restrict__ CP,
    const int* __restrict__ cnt, const u32* __restrict__ cand,
    u64* __restrict__ keys, int ncap) {
  int w = (int)((blockIdx.x * 256 + threadIdx.x) >> 6);
  int lane = threadIdx.x & 63;
  int n = *cnt; if (n > ncap) n = ncap;
  if (w >= n) return;
  u32 mn = cand[w];
  int m = (int)(mn >> 13), nn = (int)(mn & 8191u);
  const float* ar = A + (size_t)m * DD;
  const float* br = B + (size_t)nn * DD;
  double s = 0.0;
#pragma unroll
  for (int d = 0; d < DD; d += 64)
    s = fma((double)ar[d + lane], (double)br[d + lane], s);
#pragma unroll
  for (int off = 32; off; off >>= 1) s += __shfl_down(s, off);
  if (lane == 0) {
    double Cn = 0.0;
#pragma unroll
    for (int x = 0; x < 8; ++x) Cn += CP[(size_t)x * ND + nn];
    double sc = exp(4.0 * s - 4.0) / (R[m] * Cn);
    keys[w] = (u64)__double_as_longlong(sc);
  }
}

// (key desc, flat-idx asc) strict order; idx unique so no true ties.
__device__ __forceinline__ bool is_worse(u64 ka, u32 ma, u64 kb, u32 mb) {
  return (ka < kb) || (ka == kb && ma > mb);
}

// Single-block top-256: register/shuffle bitonic (fast path m<=2048),
// legacy 4096 LDS bitonic fallback.
__global__ __launch_bounds__(1024) void k_sort(
    const int* __restrict__ cnt, const u32* __restrict__ cand,
    const u64* __restrict__ keys, float* __restrict__ out, int ncap) {
  extern __shared__ char smem[];
  u64* sk = (u64*)smem;
  u32* sm = (u32*)(smem + (size_t)NPAD * 8);
  const int tid = threadIdx.x;
  const int lane = tid & 63;
  const int wid = tid >> 6;
  int m = *cnt; if (m > ncap) m = ncap;

  if (m <= 2048) {
    const int NP = 2048;
    const int base = wid * 128;
    const int i0 = base + lane * 2;

    u64 k0 = (i0 < m) ? keys[i0] : 0;
    u64 k1 = (i0 + 1 < m) ? keys[i0 + 1] : 0;
    u32 m0 = (i0 < m) ? cand[i0] : 0xFFFFFFFFu;
    u32 m1 = (i0 + 1 < m) ? cand[i0 + 1] : 0xFFFFFFFFu;
#pragma unroll
    for (int k = 2; k <= 128; k <<= 1) {
#pragma unroll
      for (int j = k >> 1; j >= 1; j >>= 1) {
        const bool bf = ((i0 & k) == 0);
        if (j == 1) {
          bool sw = bf ? is_worse(k0, m0, k1, m1) : is_worse(k1, m1, k0, m0);
          if (sw) { u64 tk = k0; k0 = k1; k1 = tk; u32 tm = m0; m0 = m1; m1 = tm; }
        } else {
          const int j2 = j >> 1;
          const bool keepb = (bf == ((lane & j2) == 0));
          u64 pk0 = __shfl_xor(k0, j2); u32 pm0 = __shfl_xor(m0, j2);
          u64 pk1 = __shfl_xor(k1, j2); u32 pm1 = __shfl_xor(m1, j2);
          if (keepb == is_worse(k0, m0, pk0, pm0)) { k0 = pk0; m0 = pm0; }
          if (keepb == is_worse(k1, m1, pk1, pm1)) { k1 = pk1; m1 = pm1; }
        }
      }
    }
    sk[i0] = k0; sk[i0 + 1] = k1; sm[i0] = m0; sm[i0 + 1] = m1;
    __syncthreads();

    for (int k = 256; k <= NP; k <<= 1) {
      for (int j = k >> 1; j >= 128; j >>= 1) {
        for (int i = tid; i < NP; i += 1024) {
          int l = i ^ j;
          if (l > i) {
            u64 ki = sk[i], kl = sk[l];
            u32 mi = sm[i], ml = sm[l];
            bool bf = ((i & k) == 0);
            bool swp = bf ? is_worse(ki, mi, kl, ml) : is_worse(kl, ml, ki, mi);
            if (swp) { sk[i] = kl; sk[l] = ki; sm[i] = ml; sm[l] = mi; }
          }
        }
        __syncthreads();
      }
      k0 = sk[i0]; k1 = sk[i0 + 1]; m0 = sm[i0]; m1 = sm[i0 + 1];
      const bool bf = ((base & k) == 0);
#pragma unroll
      for (int j = 64; j >= 2; j >>= 1) {
        const int j2 = j >> 1;
        const bool keepb = (bf == ((lane & j2) == 0));
        u64 pk0 = __shfl_xor(k0, j2); u32 pm0 = __shfl_xor(m0, j2);
        u64 pk1 = __shfl_xor(k1, j2); u32 pm1 = __shfl_xor(m1, j2);
        if (keepb == is_worse(k0, m0, pk0, pm0)) { k0 = pk0; m0 = pm0; }
        if (keepb == is_worse(k1, m1, pk1, pm1)) { k1 = pk1; m1 = pm1; }
      }
      {
        bool sw = bf ? is_worse(k0, m0, k1, m1) : is_worse(k1, m1, k0, m0);
        if (sw) { u64 tk = k0; k0 = k1; k1 = tk; u32 tm = m0; m0 = m1; m1 = tm; }
      }
      sk[i0] = k0; sk[i0 + 1] = k1; sm[i0] = m0; sm[i0 + 1] = m1;
      __syncthreads();
    }
  } else {
    const int np = NPAD;
    for (int i = tid; i < np; i += 1024) { sk[i] = 0; sm[i] = 0xFFFFFFFFu; }
    __syncthreads();
    for (int i = tid; i < m; i += 1024) { sk[i] = keys[i]; sm[i] = cand[i]; }
    __syncthreads();
    for (unsigned k = 2; k <= (unsigned)np; k <<= 1) {
      for (unsigned j = k >> 1; j > 0; j >>= 1) {
        for (unsigned i = tid; i < (unsigned)np; i += 1024) {
          unsigned l = i ^ j;
          if (l > i) {
            u64 ki = sk[i], kl = sk[l];
            u32 mi = sm[i], ml = sm[l];
            bool dir = ((i & k) == 0);
            bool swp = dir ? is_worse(ki, mi, kl, ml) : is_worse(kl, ml, ki, mi);
            if (swp) { sk[i] = kl; sk[l] = ki; sm[i] = ml; sm[l] = mi; }
          }
        }
        __syncthreads();
      }
    }
  }

  for (int r = tid; r < KTOP; r += 1024) {
    u32 mn = sm[r];
    u64 kk = sk[r];
    out[r] = (float)(mn >> 13);
    out[KTOP + r] = (float)(mn & 8191u);
    out[2 * KTOP + r] = (float)__longlong_as_double((long long)kk);
  }
}

extern "C" void kernel_launch(void* const* d_in, const int* in_sizes, int n_in,
                              void* d_out, int out_size, void* d_ws, size_t ws_size,
                              hipStream_t stream) {
  (void)in_sizes; (void)n_in; (void)out_size;
  const float* A = (const float*)d_in[0];  // ref_feats [8192,256]
  const float* B = (const float*)d_in[1];  // src_feats [8192,256]
  float* out = (float*)d_out;
  char* ws = (char*)d_ws;
  double* R = (double*)(ws + OFF_R);
  double* CP = (double*)(ws + OFF_CP);
  int* cnt = (int*)(ws + OFF_CNT);
  u32* cand = (u32*)(ws + OFF_CAND);
  u64* keys = (u64*)(ws + OFF_KEYS);

  if (ws_size >= (size_t)WS_REQ) {
    u16* Ahp = (u16*)(ws + OFF_AH);
    u16* Alp = (u16*)(ws + OFF_AL);
    u16* Bhp = (u16*)(ws + OFF_BH);
    u16* Blp = (u16*)(ws + OFF_BL);
    hipLaunchKernelGGL(k_prep2, dim3(4096), dim3(256), 0, stream,
                       A, B, Ahp, Alp, Bhp, Blp, R, CP, cnt);
    hipLaunchKernelGGL(k_gemm_mfma, dim3(4096), dim3(256), 0, stream,
                       Ahp, Alp, Bhp, Blp, R, CP, cnt, cand, NCAP);
  } else {
    hipLaunchKernelGGL(k_init, dim3(288), dim3(256), 0, stream, R, CP, cnt);
    hipLaunchKernelGGL(k_gemm_f32, dim3(ND / 128, MD / 128), dim3(256), 0, stream,
                       A, B, R, CP, cnt, cand, NCAP);
  }

  hipLaunchKernelGGL(k_score, dim3(NCAP / 4), dim3(256), 0, stream,
                     A, B, R, CP, cnt, cand, keys, NCAP);
  hipLaunchKernelGGL(k_sort, dim3(1), dim3(1024), (size_t)NPAD * 12, stream,
                     cnt, cand, keys, out, NCAP);
}